// Round 4
// baseline (7760.044 us; speedup 1.0000x reference)
//
#include <hip/hip_runtime.h>
#include <cmath>

typedef __bf16 bf16;
typedef float f32x4 __attribute__((ext_vector_type(4)));
typedef bf16 bf16x8 __attribute__((ext_vector_type(8)));
typedef bf16 bf16x2 __attribute__((ext_vector_type(2)));

#define DEVINL __device__ __forceinline__

DEVINL void gload_lds16(const void* g, void* l) {
  __builtin_amdgcn_global_load_lds(
      (const __attribute__((address_space(1))) void*)g,
      (__attribute__((address_space(3))) void*)l, 16, 0, 0);
}

DEVINL float sigf(float x) { return 1.f / (1.f + __expf(-x)); }

// ---------------- fused prep: all weight casts + x prep + barrier zero ----------
__global__ void prep_all_k(
    const float* __restrict__ x,
    const float* __restrict__ eWih0, const float* __restrict__ eWhh0,
    const float* __restrict__ eWih1, const float* __restrict__ eWhh1,
    const float* __restrict__ dWih0, const float* __restrict__ dWhh0,
    const float* __restrict__ dWih1, const float* __restrict__ dWhh1,
    const float* __restrict__ fcW,
    bf16* __restrict__ Wih_e0, bf16* __restrict__ Whh_e0, bf16* __restrict__ Wcat_e1,
    bf16* __restrict__ Wih_d0, bf16* __restrict__ Whh_d0, bf16* __restrict__ Wcat_d1,
    bf16* __restrict__ Wfc, bf16* __restrict__ xe, bf16* __restrict__ xd,
    unsigned* __restrict__ bars) {
  int i = blockIdx.x * 256 + threadIdx.x;
  if (i == 0) { bars[0] = 0; bars[1] = 0; }
  if (i < 2097152) { Wih_e0[i] = (bf16)eWih0[i]; return; }
  i -= 2097152;
  if (i < 4194304) { Whh_e0[i] = (bf16)eWhh0[i]; return; }
  i -= 4194304;
  if (i < 8388608) {
    int k = i & 2047, r = i >> 11;
    Wcat_e1[i] = (bf16)((k < 1024) ? eWih1[r * 1024 + k] : eWhh1[r * 1024 + k - 1024]);
    return;
  }
  i -= 8388608;
  if (i < 2097152) { Wih_d0[i] = (bf16)dWih0[i]; return; }
  i -= 2097152;
  if (i < 4194304) { Whh_d0[i] = (bf16)dWhh0[i]; return; }
  i -= 4194304;
  if (i < 8388608) {
    int k = i & 2047, r = i >> 11;
    Wcat_d1[i] = (bf16)((k < 1024) ? dWih1[r * 1024 + k] : dWhh1[r * 1024 + k - 1024]);
    return;
  }
  i -= 8388608;
  if (i < 524288) { Wfc[i] = (bf16)fcW[i]; return; }
  i -= 524288;
  if (i < 4194304) {
    int ii = i & 511;
    int b = (i >> 9) & 63;
    int t = i >> 15;
    xe[i] = (bf16)x[b * 65536 + t * 512 + ii];
    xd[i] = (t == 0) ? (bf16)0.f : (bf16)x[b * 65536 + (t - 1) * 512 + ii];
  }
}

// ---------------- big GEMM: C[M,N] = A[M,K] @ W[N,K]^T (bf16 in, f32 acc) ----------
__global__ __launch_bounds__(256) void gemm_bt_k(
    const bf16* __restrict__ A, const bf16* __restrict__ Bw,
    bf16* __restrict__ Cbf, float* __restrict__ Cf32, const float* __restrict__ bias,
    int M, int N, int K, int mode) {
  __shared__ __attribute__((aligned(16))) bf16 As[128 * 32];
  __shared__ __attribute__((aligned(16))) bf16 Bs[128 * 32];
  const int tid = threadIdx.x;
  const int lane = tid & 63;
  const int wave = tid >> 6;
  const int wm = wave >> 1, wn = wave & 1;
  const int m0 = blockIdx.y * 128;
  const int n0 = blockIdx.x * 128;

  f32x4 acc[4][4];
  for (int i = 0; i < 4; ++i)
    for (int j = 0; j < 4; ++j) acc[i][j] = 0;

  const int r1 = tid >> 2;
  const int kc = (tid & 3) * 8;
  const int fr = lane & 15;
  const int fk = (lane >> 4) * 8;

  for (int k0 = 0; k0 < K; k0 += 32) {
    gload_lds16(A + (size_t)(m0 + r1) * K + k0 + kc, As + tid * 8);
    gload_lds16(A + (size_t)(m0 + 64 + r1) * K + k0 + kc, As + 2048 + tid * 8);
    gload_lds16(Bw + (size_t)(n0 + r1) * K + k0 + kc, Bs + tid * 8);
    gload_lds16(Bw + (size_t)(n0 + 64 + r1) * K + k0 + kc, Bs + 2048 + tid * 8);
    __syncthreads();
    bf16x8 af[4], bw[4];
    for (int i = 0; i < 4; ++i)
      af[i] = *(const bf16x8*)(As + (wm * 64 + i * 16 + fr) * 32 + fk);
    for (int j = 0; j < 4; ++j)
      bw[j] = *(const bf16x8*)(Bs + (wn * 64 + j * 16 + fr) * 32 + fk);
    for (int i = 0; i < 4; ++i)
      for (int j = 0; j < 4; ++j)
        acc[i][j] = __builtin_amdgcn_mfma_f32_16x16x32_bf16(af[i], bw[j], acc[i][j], 0, 0, 0);
    __syncthreads();
  }

  const int col16 = lane & 15;
  const int rq = (lane >> 4) * 4;
  for (int i = 0; i < 4; ++i)
    for (int j = 0; j < 4; ++j)
      for (int r = 0; r < 4; ++r) {
        int row = m0 + wm * 64 + i * 16 + rq + r;
        int col = n0 + wn * 64 + j * 16 + col16;
        float v = acc[i][j][r];
        if (mode == 0) {
          Cbf[(size_t)row * N + col] = (bf16)v;
        } else {
          v = sigf(v + bias[col]);
          int b = row & 63, t = row >> 6;
          Cf32[(size_t)b * (128 * 512) + (size_t)t * 512 + col] = v;
        }
      }
}

// ---------------- persistent two-layer phase kernel (cooperative) ----------------
// 256 WGs x 256 thr, 1 WG/CU. WGs 0..127 = layer A (K=1024, gates = G[t] +
// h@WhhA^T). WGs 128..255 = layer B at t-1 (K=2048 concat[RA[t], hB]@WcatB^T).
// h exchanged through depth-128 rings: written once with 4B relaxed agent-scope
// atomic stores (land at L3 coherence point, no wbl2), read once with plain
// loads at fresh addresses (no stale L2 line possible; first touch per XCD
// pulls L3->L2, then 32 WGs share). Grid barrier = single relaxed agent-scope
// counter, no fences; __syncthreads before signal drains vmcnt (compiler emits
// s_waitcnt vmcnt(0) before s_barrier). Weights stay L2-resident all 129 steps.
__global__ __launch_bounds__(256, 1) void phase_k(
    const bf16* __restrict__ G, const bf16* __restrict__ WhhA,
    const float* __restrict__ biasA, const bf16* __restrict__ hA0,
    const float* __restrict__ cA0, bf16* __restrict__ RA,
    const bf16* __restrict__ WcatB, const float* __restrict__ biasB,
    const bf16* __restrict__ hB0, const float* __restrict__ cB0,
    bf16* __restrict__ RB, bf16* __restrict__ HfinA, bf16* __restrict__ HfinB,
    unsigned* __restrict__ bar) {
  __shared__ float gt[2][64][33];
  const int tid = threadIdx.x;
  const int lane = tid & 63;
  const int wave = tid >> 6;
  const int ct = wave & 1;
  const int kw = wave >> 1;
  const int half = blockIdx.x >> 7;
  const int j0 = (blockIdx.x & 127) * 8;
  const int fr = lane & 15;
  const int fk = (lane >> 4) * 8;
  const int rq = (lane >> 4) * 4;
  const int ccol = ct * 16 + fr;                          // gate-col 0..31
  const int nrow = (ccol >> 3) * 1024 + j0 + (ccol & 7);  // weight row
  const int cb = tid >> 2;                                // cell batch
  const int cj = (tid & 3) * 2;                           // cell col pair

  const float* bias = half ? biasB : biasA;
  const float* c0 = half ? cB0 : cA0;
  bf16* R = half ? RB : RA;
  bf16* Hfin = half ? HfinB : HfinA;

  float bsr[4][2];
#pragma unroll
  for (int g = 0; g < 4; ++g) {
    bsr[g][0] = bias[g * 1024 + j0 + cj];
    bsr[g][1] = bias[g * 1024 + j0 + cj + 1];
  }
  float creg[2];
  if (c0) {
    creg[0] = c0[cb * 1024 + j0 + cj];
    creg[1] = c0[cb * 1024 + j0 + cj + 1];
  } else {
    creg[0] = creg[1] = 0.f;
  }

  const bf16* wpA = WhhA + (size_t)nrow * 1024 + kw * 512 + fk;
  const bf16* wpB = WcatB + (size_t)nrow * 2048 + kw * 1024 + fk;

  for (int d = 0; d <= 128; ++d) {
    const int t = half ? (d - 1) : d;
    const bool active = half ? (d >= 1) : (d < 128);
    if (active) {
      f32x4 acc[4];
      acc[0] = 0; acc[1] = 0; acc[2] = 0; acc[3] = 0;
      float gx[4][2] = {{0, 0}, {0, 0}, {0, 0}, {0, 0}};

      if (half == 0) {
        const bf16* Gt = G + (size_t)t * 262144 + (size_t)cb * 4096;
#pragma unroll
        for (int g = 0; g < 4; ++g) {
          bf16x2 g2 = *(const bf16x2*)(Gt + g * 1024 + j0 + cj);
          gx[g][0] = (float)g2.x;
          gx[g][1] = (float)g2.y;
        }
        const bf16* hp = (t == 0) ? hA0 : (RA + (size_t)(t - 1) * 65536);
        if (hp) {
          const bf16* ap = hp + fr * 1024 + kw * 512 + fk;
#pragma unroll
          for (int kk = 0; kk < 16; ++kk) {
            bf16x8 bw = *(const bf16x8*)(wpA + kk * 32);
            bf16x8 a0 = *(const bf16x8*)(ap + kk * 32);
            bf16x8 a1 = *(const bf16x8*)(ap + 16 * 1024 + kk * 32);
            bf16x8 a2 = *(const bf16x8*)(ap + 32 * 1024 + kk * 32);
            bf16x8 a3 = *(const bf16x8*)(ap + 48 * 1024 + kk * 32);
            acc[0] = __builtin_amdgcn_mfma_f32_16x16x32_bf16(a0, bw, acc[0], 0, 0, 0);
            acc[1] = __builtin_amdgcn_mfma_f32_16x16x32_bf16(a1, bw, acc[1], 0, 0, 0);
            acc[2] = __builtin_amdgcn_mfma_f32_16x16x32_bf16(a2, bw, acc[2], 0, 0, 0);
            acc[3] = __builtin_amdgcn_mfma_f32_16x16x32_bf16(a3, bw, acc[3], 0, 0, 0);
          }
        }
      } else {
        // kw=0: k 0..1023 from RA[t] (layer A output, this phase);
        // kw=1: k 1024..2047 from own h: hB0 at t=0, else RB[t-1]
        const bf16* src = (kw == 0) ? (RA + (size_t)t * 65536)
                                    : ((t == 0) ? hB0 : (RB + (size_t)(t - 1) * 65536));
        if (src) {
          const bf16* ap = src + fr * 1024 + fk;
#pragma unroll
          for (int kk = 0; kk < 32; ++kk) {
            bf16x8 bw = *(const bf16x8*)(wpB + kk * 32);
            bf16x8 a0 = *(const bf16x8*)(ap + kk * 32);
            bf16x8 a1 = *(const bf16x8*)(ap + 16 * 1024 + kk * 32);
            bf16x8 a2 = *(const bf16x8*)(ap + 32 * 1024 + kk * 32);
            bf16x8 a3 = *(const bf16x8*)(ap + 48 * 1024 + kk * 32);
            acc[0] = __builtin_amdgcn_mfma_f32_16x16x32_bf16(a0, bw, acc[0], 0, 0, 0);
            acc[1] = __builtin_amdgcn_mfma_f32_16x16x32_bf16(a1, bw, acc[1], 0, 0, 0);
            acc[2] = __builtin_amdgcn_mfma_f32_16x16x32_bf16(a2, bw, acc[2], 0, 0, 0);
            acc[3] = __builtin_amdgcn_mfma_f32_16x16x32_bf16(a3, bw, acc[3], 0, 0, 0);
          }
        }
      }

      // stage partial gate sums: gt[kw][batch][gate-col]
#pragma unroll
      for (int bt = 0; bt < 4; ++bt)
#pragma unroll
        for (int r = 0; r < 4; ++r)
          gt[kw][bt * 16 + rq + r][ct * 16 + fr] = acc[bt][r];
      __syncthreads();

      // cell update (thread owns b=cb, cols j0+cj, j0+cj+1; c register-resident)
      float hn[2];
#pragma unroll
      for (int r = 0; r < 2; ++r) {
        int jj = cj + r;
        float gi = gt[0][cb][jj]      + gt[1][cb][jj]      + gx[0][r] + bsr[0][r];
        float gf = gt[0][cb][8 + jj]  + gt[1][cb][8 + jj]  + gx[1][r] + bsr[1][r];
        float gg = gt[0][cb][16 + jj] + gt[1][cb][16 + jj] + gx[2][r] + bsr[2][r];
        float go = gt[0][cb][24 + jj] + gt[1][cb][24 + jj] + gx[3][r] + bsr[3][r];
        float cn = sigf(gf) * creg[r] + sigf(gi) * tanhf(gg);
        creg[r] = cn;
        hn[r] = sigf(go) * tanhf(cn);
      }
      union { bf16 h[2]; unsigned u; } pk;
      pk.h[0] = (bf16)hn[0];
      pk.h[1] = (bf16)hn[1];
      __hip_atomic_store((unsigned*)(R + (size_t)t * 65536 + cb * 1024 + j0 + cj),
                         pk.u, __ATOMIC_RELAXED, __HIP_MEMORY_SCOPE_AGENT);
      if (Hfin && t == 127) {
        bf16x2 e2; e2.x = (bf16)tanhf(hn[0]); e2.y = (bf16)tanhf(hn[1]);
        *(bf16x2*)(Hfin + cb * 1024 + j0 + cj) = e2;
      }
    }

    // grid barrier: syncthreads drains each wave's vmcnt; relaxed agent atomics
    __syncthreads();
    if (tid == 0) {
      __hip_atomic_fetch_add(bar, 1u, __ATOMIC_RELAXED, __HIP_MEMORY_SCOPE_AGENT);
      const unsigned tgt = (unsigned)(d + 1) * 256u;
      while (__hip_atomic_load(bar, __ATOMIC_RELAXED, __HIP_MEMORY_SCOPE_AGENT) < tgt)
        __builtin_amdgcn_s_sleep(2);
    }
    __syncthreads();
  }
}

// ---------------- host orchestration ----------------
extern "C" void kernel_launch(void* const* d_in, const int* in_sizes, int n_in,
                              void* d_out, int out_size, void* d_ws, size_t ws_size,
                              hipStream_t stream) {
  (void)in_sizes; (void)n_in; (void)out_size; (void)ws_size;
  const float* x      = (const float*)d_in[0];
  const float* dec_c0 = (const float*)d_in[1];
  const float* eWih0 = (const float*)d_in[2];
  const float* eWhh0 = (const float*)d_in[3];
  const float* eb0   = (const float*)d_in[4];
  const float* eWih1 = (const float*)d_in[5];
  const float* eWhh1 = (const float*)d_in[6];
  const float* eb1   = (const float*)d_in[7];
  const float* dWih0 = (const float*)d_in[8];
  const float* dWhh0 = (const float*)d_in[9];
  const float* db0   = (const float*)d_in[10];
  const float* dWih1 = (const float*)d_in[11];
  const float* dWhh1 = (const float*)d_in[12];
  const float* db1   = (const float*)d_in[13];
  const float* fcW   = (const float*)d_in[14];
  const float* fcb   = (const float*)d_in[15];
  float* out = (float*)d_out;

  const int H = 1024, I = 512, T = 128, B = 64;
  const int BH = B * H;
  const size_t TBI = (size_t)T * B * I;
  const size_t TBH = (size_t)T * B * H;

  char* p = (char*)d_ws;
  auto alloc = [&](size_t bytes) -> char* {
    char* r = p; p += (bytes + 255) & ~(size_t)255; return r;
  };
  bf16* Wih_e0 = (bf16*)alloc((size_t)4 * H * I * 2);
  bf16* Whh_e0 = (bf16*)alloc((size_t)4 * H * H * 2);
  bf16* Wcat_e1 = (bf16*)alloc((size_t)4 * H * 2 * H * 2);
  bf16* Wih_d0 = (bf16*)alloc((size_t)4 * H * I * 2);
  bf16* Whh_d0 = (bf16*)alloc((size_t)4 * H * H * 2);
  bf16* Wcat_d1 = (bf16*)alloc((size_t)4 * H * 2 * H * 2);
  bf16* Wfc = (bf16*)alloc((size_t)I * H * 2);
  bf16* xe = (bf16*)alloc(TBI * 2);
  bf16* xd = (bf16*)alloc(TBI * 2);
  bf16* G  = (bf16*)alloc((size_t)T * B * 4 * H * 2);   // 64 MB
  bf16* ring0 = (bf16*)alloc(TBH * 2);                  // layer-A ring (enc S0 / dec S0)
  bf16* ring1 = (bf16*)alloc(TBH * 2);                  // layer-B ring (enc L1 h / dec S1)
  bf16* henc0 = (bf16*)alloc((size_t)BH * 2);
  bf16* henc1 = (bf16*)alloc((size_t)BH * 2);
  unsigned* bars = (unsigned*)alloc(256);

  // fused prep (34,078,720 work items)
  prep_all_k<<<133120, 256, 0, stream>>>(x, eWih0, eWhh0, eWih1, eWhh1,
                                         dWih0, dWhh0, dWih1, dWhh1, fcW,
                                         Wih_e0, Whh_e0, Wcat_e1,
                                         Wih_d0, Whh_d0, Wcat_d1,
                                         Wfc, xe, xd, bars);

  auto coop = [&](const bf16* Gp, const bf16* WhhAp, const float* biasAp,
                  const bf16* hA0p, const float* cA0p, bf16* RAp,
                  const bf16* WcatBp, const float* biasBp, const bf16* hB0p,
                  const float* cB0p, bf16* RBp, bf16* HfA, bf16* HfB,
                  unsigned* barp) {
    void* args[] = { (void*)&Gp, (void*)&WhhAp, (void*)&biasAp, (void*)&hA0p,
                     (void*)&cA0p, (void*)&RAp, (void*)&WcatBp, (void*)&biasBp,
                     (void*)&hB0p, (void*)&cB0p, (void*)&RBp, (void*)&HfA,
                     (void*)&HfB, (void*)&barp };
    hipLaunchCooperativeKernel((void*)phase_k, dim3(256), dim3(256), args, 0, stream);
  };

  // ---- encoder: pre-GEMM (L0 input side) + persistent 2-layer phase ----
  gemm_bt_k<<<dim3(32, 64), 256, 0, stream>>>(xe, Wih_e0, G, nullptr, nullptr,
                                              8192, 4096, 512, 0);
  coop(G, Whh_e0, eb0, nullptr, nullptr, ring0,
       Wcat_e1, eb1, nullptr, nullptr, ring1, henc0, henc1, bars + 0);

  // ---- decoder: pre-GEMM (L0 input side) + persistent 2-layer phase ----
  gemm_bt_k<<<dim3(32, 64), 256, 0, stream>>>(xd, Wih_d0, G, nullptr, nullptr,
                                              8192, 4096, 512, 0);
  coop(G, Whh_d0, db0, henc0, dec_c0, ring0,
       Wcat_d1, db1, henc1, dec_c0 + BH, ring1, nullptr, nullptr, bars + 1);

  // ---- FC: sigmoid(ring1 @ fcW^T + fcb), permute [t,b]->[b,t] ----
  gemm_bt_k<<<dim3(4, 64), 256, 0, stream>>>(ring1, Wfc, nullptr, out, fcb,
                                             8192, 512, 1024, 1);
}